// Round 4
// baseline (3994.319 us; speedup 1.0000x reference)
//
#include <hip/hip_runtime.h>

typedef _Float16 half8 __attribute__((ext_vector_type(8)));
typedef float    f32x4 __attribute__((ext_vector_type(4)));
typedef unsigned int u32;
typedef unsigned long long u64;

#define B_   1024
#define T_   256
#define U_   512

// 64 groups x 8 WGs; group owns 16 batch rows, WG owns u-slice of 64.
// 512 blocks total = 2 blocks/CU (launch_bounds-enforced) -> one block's
// compute hides the other's IC exchange latency.
#define PER_G  8
#define ROWS_G 16
#define NGRP   64
#define U_WG   64

// d_ws layout
static const size_t WHT_OFF = 0;                 // WhT fp16 [2048][512] = 2 MB
static const size_t H_OFF   = 2u*1024*1024;      // h ping-pong fp16 [2][1024][512] = 2 MB
static const size_t CTR_OFF = 4u*1024*1024;      // ctr u32 [64][8] flags
static const size_t PT_OFF  = 4u*1024*1024 + 65536;  // pricesT f32 [256][1024] = 1 MB

__global__ __launch_bounds__(512)
void prep_wht(const float* __restrict__ Wh, _Float16* __restrict__ WhT) {
  int j = blockIdx.x;   // 0..2047
  int k = threadIdx.x;  // 0..511
  WhT[(size_t)j*U_ + k] = (_Float16)Wh[(size_t)k*(4*U_) + j];
}

__global__ __launch_bounds__(256)
void prep_pt(const float* __restrict__ prices, float* __restrict__ pricesT) {
  int t = blockIdx.x;                 // 0..255
  for (int r = threadIdx.x; r < B_; r += 256)
    pricesT[(size_t)t*B_ + r] = prices[(size_t)r*T_ + t];
}

__device__ __forceinline__ float sigm(float x) { return 1.f/(1.f + __expf(-x)); }
__device__ __forceinline__ float tanhf_fast(float x) {
  float ax = fabsf(x);
  float e  = __expf(2.f*ax);          // large ax -> inf -> t = 1 (safe)
  float t  = 1.f - 2.f/(e + 1.f);
  return copysignf(t, x);
}

// Agent-scope (IC-coherent) fine-grain ops — baseline-proven; no cache-bit games.
__device__ __forceinline__ u64 ld_agent_u64(const void* p) {
  return __hip_atomic_load((const u64*)p, __ATOMIC_RELAXED, __HIP_MEMORY_SCOPE_AGENT);
}
__device__ __forceinline__ void st_agent_u64(void* p, u64 v) {
  __hip_atomic_store((u64*)p, v, __ATOMIC_RELAXED, __HIP_MEMORY_SCOPE_AGENT);
}
__device__ __forceinline__ void st_agent_u32(void* p, u32 v) {
  __hip_atomic_store((u32*)p, v, __ATOMIC_RELAXED, __HIP_MEMORY_SCOPE_AGENT);
}
__device__ __forceinline__ u32 ld_agent_u32(const void* p) {
  return __hip_atomic_load((const u32*)p, __ATOMIC_RELAXED, __HIP_MEMORY_SCOPE_AGENT);
}

// Persistent LSTM: 512 WGs x 512 thr, 2 WGs/CU.  WG (gid = b>>3, j = b&7):
// rows [gid*16,+16), u [j*64,+64).
// Wave w: gate g = w&3, col-half cph = w>>2 (cols [cph*32,+32)).
// Each wave: FULL K=512 chain (baseline-verbatim arithmetic), 1 row-tile x
// 2 col-tiles, bf[16][2] = 128 VGPR resident.
// Exchange via agent-scope ops at IC; flags ctr[gid][8], value = steps done.
// __launch_bounds__(512,4): 4 waves/SIMD -> <=128 VGPR -> 2 blocks/CU
// guaranteed schedulable (LDS 33.8KB x2 = 67.5KB <= 160KB).
__global__ __launch_bounds__(512, 4)
void lstm_persist(const float* __restrict__ pricesT,
                  const float* __restrict__ Wx,
                  const float* __restrict__ bias,
                  const float* __restrict__ Wd,
                  const float* __restrict__ bd,
                  const float* __restrict__ Wp,
                  const float* __restrict__ bp,
                  const _Float16* __restrict__ WhT,
                  _Float16* __restrict__ hbuf,      // [2][1024][512]
                  u32* __restrict__ ctr,            // [64][8]
                  float* __restrict__ out)          // [1024][32]
{
  __shared__ __align__(16) _Float16 hs[ROWS_G][520];   // 16.6 KB
  __shared__ __align__(16) float    gz[4][ROWS_G][66]; // 16.9 KB
  __shared__ float ps[ROWS_G];

  const int tid = threadIdx.x;
  const int b   = blockIdx.x;
  const int gid = b >> 3;           // group 0..63
  const int j   = b & 7;            // WG within group
  const int row0 = gid * ROWS_G;
  const int u0   = j * U_WG;

  const int wv8 = tid >> 6;         // wave 0..7
  const int g   = wv8 & 3;          // gate 0..3
  const int cph = wv8 >> 2;         // col-half 0..1 (32 cols each)
  const int ln  = tid & 15;
  const int qd  = (tid >> 4) & 3;

  // ---- Wh slab -> B-fragments (128 VGPR): B[k = kk*32 + qd*8 + jj][n = ln] ----
  half8 bf[16][2];
  #pragma unroll
  for (int kk = 0; kk < 16; ++kk) {
    #pragma unroll
    for (int ct = 0; ct < 2; ++ct) {
      int gcol = g*U_ + u0 + cph*32 + ct*16 + ln;   // global gate-col
      bf[kk][ct] = *(const half8*)&WhT[(size_t)gcol*U_ + kk*32 + qd*8];
    }
  }

  // gate-stage mapping: thread (tid<256) owns (row = tid&15, u4 = ((tid>>4)&15)*4)
  const int grow = tid & 15;
  const int gu4  = ((tid >> 4) & 15) * 4;   // 0..60 step 4
  float wxv[4][4], bv[4][4];
  #pragma unroll
  for (int gg = 0; gg < 4; ++gg)
    #pragma unroll
    for (int jj = 0; jj < 4; ++jj) {
      int ug = u0 + gu4 + jj;
      wxv[gg][jj] = Wx[gg*U_ + ug];
      bv[gg][jj]  = bias[gg*U_ + ug];
    }

  float c[4];
  #pragma unroll
  for (int e = 0; e < 4; ++e) c[e] = 0.f;

  u32* const myfl = ctr + gid*PER_G;

  for (int t = 0; t < T_; ++t) {
    const _Float16* hcur = hbuf + (size_t)(t & 1)*(B_*U_) + (size_t)row0*U_;
    _Float16* hnxt = hbuf + (size_t)((t + 1) & 1)*(B_*U_);

    // ---- wait: all 8 peers posted h(t) (flag >= t); wave 0 only ----
    if (wv8 == 0) {
      const int lane = tid & 63;
      bool ok;
      do {
        u32 v = (lane < PER_G) ? ld_agent_u32(&myfl[lane]) : 0xFFFFFFFFu;
        ok = (v >= (u32)t);
        if (!__all(ok)) { __builtin_amdgcn_s_sleep(1); ok = false; }
        else ok = true;
      } while (!ok);
      if (tid < ROWS_G) ps[tid] = pricesT[(size_t)t*B_ + row0 + tid];
    }
    __syncthreads();

    // ---- stage h tile: 16 rows x 512 halves = 2048 chunks of 8B ----
    #pragma unroll
    for (int it = 0; it < 4; ++it) {
      int id = tid + it*512;        // 0..2047
      int r  = id >> 7;             // row 0..15
      int ch = id & 127;            // 8B chunk
      u64 v = ld_agent_u64(&hcur[(size_t)r*U_ + ch*4]);
      *(u64*)&hs[r][ch*4] = v;
    }
    __syncthreads();

    // ---- z = h @ Wh: gate g, rows 16, cols [cph*32,+32), FULL K=512 chain ----
    f32x4 acc[2];
    #pragma unroll
    for (int ct = 0; ct < 2; ++ct)
      #pragma unroll
      for (int r = 0; r < 4; ++r)
        acc[ct][r] = 0.f;

    #pragma unroll
    for (int kk = 0; kk < 16; ++kk) {
      half8 afr = *(const half8*)&hs[ln][kk*32 + qd*8];  // A[m=ln][k=qd*8+jj]
      acc[0] = __builtin_amdgcn_mfma_f32_16x16x32_f16(afr, bf[kk][0], acc[0], 0, 0, 0);
      acc[1] = __builtin_amdgcn_mfma_f32_16x16x32_f16(afr, bf[kk][1], acc[1], 0, 0, 0);
    }

    // ---- scatter z (C/D: row = qd*4+r, col = ln) ----
    #pragma unroll
    for (int ct = 0; ct < 2; ++ct)
      #pragma unroll
      for (int r = 0; r < 4; ++r)
        gz[g][qd*4 + r][cph*32 + ct*16 + ln] = acc[ct][r];
    __syncthreads();

    // ---- gate math (fp32, tid<256); one packed 4xfp16 8B store per thread ----
    if (tid < 256) {
      float px = ps[grow];
      unsigned short hb[4];
      #pragma unroll
      for (int jj = 0; jj < 4; ++jj) {
        float zi = gz[0][grow][gu4+jj] + px*wxv[0][jj] + bv[0][jj];
        float zf = gz[1][grow][gu4+jj] + px*wxv[1][jj] + bv[1][jj];
        float zg = gz[2][grow][gu4+jj] + px*wxv[2][jj] + bv[2][jj];
        float zo = gz[3][grow][gu4+jj] + px*wxv[3][jj] + bv[3][jj];
        float ig = sigm(zi), fg = sigm(zf), gg = tanhf_fast(zg), og = sigm(zo);
        float cn = fg*c[jj] + ig*gg;
        c[jj] = cn;
        _Float16 hh = (_Float16)(og*tanhf_fast(cn));
        hb[jj] = __builtin_bit_cast(unsigned short, hh);
      }
      u64 pk = (u64)hb[0] | ((u64)hb[1] << 16) | ((u64)hb[2] << 32) | ((u64)hb[3] << 48);
      st_agent_u64(&hnxt[(size_t)(row0 + grow)*U_ + u0 + gu4], pk);
    }

    // ---- drain (syncthreads waits vmcnt(0) per wave), then post flag = t+1 ----
    __syncthreads();
    if (tid == 0) st_agent_u32(&myfl[j], (u32)(t + 1));
  }

  // ---- wait group's final h(256) ----
  if (wv8 == 0) {
    const int lane = tid & 63;
    bool ok;
    do {
      u32 v = (lane < PER_G) ? ld_agent_u32(&myfl[lane]) : 0xFFFFFFFFu;
      ok = (v >= (u32)T_);
      if (!__all(ok)) { __builtin_amdgcn_s_sleep(1); ok = false; }
      else ok = true;
    } while (!ok);
  }
  __syncthreads();

  // ---- fused head: 2 rows: row0 + j*2 .. +2 ----
  {
    const _Float16* hfin = hbuf;                                // parity of t=256 is 0
    float*    xrow = (float*)&gz[0][0][0];                      // [2][64]
    _Float16* hrow = (_Float16*)((char*)&gz[0][0][0] + 512);    // [2][512]

    if (tid < 256) {
      int r2 = tid >> 7;           // row 0..1
      int of = (tid & 127) * 4;    // half-offset 0..508
      u64 v = ld_agent_u64(&hfin[(size_t)(row0 + j*2 + r2)*U_ + of]);
      *(u64*)&hrow[r2*U_ + of] = v;
    }
    __syncthreads();
    if (tid < 128) {
      int rr = tid >> 6;
      int kk = tid & 63;
      float a = bd[kk];
      for (int k2 = 0; k2 < U_; ++k2)
        a += (float)hrow[rr*U_ + k2] * Wd[(size_t)k2*64 + kk];
      a = fmaxf(a, 0.f);
      xrow[rr*64 + kk] = a;
    }
    __syncthreads();
    if (tid < 128 && (tid & 63) < 32) {
      int rr = tid >> 6;
      int kk = tid & 63;
      int brow = row0 + j*2 + rr;
      float o2 = bp[kk];
      #pragma unroll
      for (int j2 = 0; j2 < 64; ++j2)
        o2 += xrow[rr*64 + j2] * Wp[j2*32 + kk];
      out[(size_t)brow*32 + kk] = o2;
    }
  }
}

extern "C" void kernel_launch(void* const* d_in, const int* in_sizes, int n_in,
                              void* d_out, int out_size, void* d_ws, size_t ws_size,
                              hipStream_t stream) {
  (void)in_sizes; (void)n_in; (void)out_size; (void)ws_size;
  const float* prices = (const float*)d_in[0];
  const float* Wx     = (const float*)d_in[1];
  const float* Wh     = (const float*)d_in[2];
  const float* bias   = (const float*)d_in[3];
  const float* Wd     = (const float*)d_in[4];
  const float* bd     = (const float*)d_in[5];
  const float* Wp     = (const float*)d_in[6];
  const float* bp     = (const float*)d_in[7];

  char* ws = (char*)d_ws;
  _Float16* WhT  = (_Float16*)(ws + WHT_OFF);
  _Float16* hbuf = (_Float16*)(ws + H_OFF);
  u32* ctr       = (u32*)(ws + CTR_OFF);
  float* pricesT = (float*)(ws + PT_OFF);

  // zero initial h (buffer 0) and the flags (ws is re-poisoned before every launch)
  hipMemsetAsync(hbuf, 0, (size_t)B_*U_*sizeof(_Float16), stream);
  hipMemsetAsync(ctr, 0, NGRP*PER_G*sizeof(u32), stream);

  prep_wht<<<dim3(4*U_), dim3(U_), 0, stream>>>(Wh, WhT);
  prep_pt<<<dim3(T_), dim3(256), 0, stream>>>(prices, pricesT);
  lstm_persist<<<dim3(512), dim3(512), 0, stream>>>(pricesT, Wx, bias, Wd, bd, Wp, bp,
                                                    WhT, hbuf, ctr, (float*)d_out);
}

// Round 5
// 2998.472 us; speedup vs baseline: 1.3321x; 1.3321x over previous
//
#include <hip/hip_runtime.h>

typedef _Float16 half8 __attribute__((ext_vector_type(8)));
typedef float    f32x4 __attribute__((ext_vector_type(4)));
typedef unsigned int u32;
typedef unsigned long long u64;

#define B_   1024
#define T_   256
#define U_   512

// 32 groups x 8 WGs; group owns 32 batch rows, WG owns u-slice of 64.
// DUAL-GROUP: each physical WG runs TWO groups (gA and gA+16) anti-phase,
// so each group's IC exchange round-trip hides under the other's compute.
// 128 physical blocks = 16 pair-slots x 8 u-slices.
#define PER_G  8
#define ROWS_G 32
#define U_WG   64

// d_ws layout
static const size_t WHT_OFF = 0;                 // WhT fp16 [2048][512] = 2 MB
static const size_t H_OFF   = 2u*1024*1024;      // h ping-pong fp16 [2][1024][512] = 2 MB
static const size_t CTR_OFF = 4u*1024*1024;      // ctr u32 [32][8]
static const size_t PT_OFF  = 4u*1024*1024 + 65536;  // pricesT f32 [256][1024] = 1 MB

__global__ __launch_bounds__(512)
void prep_wht(const float* __restrict__ Wh, _Float16* __restrict__ WhT) {
  int j = blockIdx.x;   // 0..2047
  int k = threadIdx.x;  // 0..511
  WhT[(size_t)j*U_ + k] = (_Float16)Wh[(size_t)k*(4*U_) + j];
}

__global__ __launch_bounds__(256)
void prep_pt(const float* __restrict__ prices, float* __restrict__ pricesT) {
  int t = blockIdx.x;                 // 0..255
  for (int r = threadIdx.x; r < B_; r += 256)
    pricesT[(size_t)t*B_ + r] = prices[(size_t)r*T_ + t];
}

__device__ __forceinline__ float sigm(float x) { return 1.f/(1.f + __expf(-x)); }
__device__ __forceinline__ float tanhf_fast(float x) {
  float ax = fabsf(x);
  float e  = __expf(2.f*ax);          // large ax -> inf -> t = 1 (safe)
  float t  = 1.f - 2.f/(e + 1.f);
  return copysignf(t, x);
}

// Agent-scope (IC-coherent) fine-grain ops — round-0-proven; no cache-bit games.
__device__ __forceinline__ u64 ld_agent_u64(const void* p) {
  return __hip_atomic_load((const u64*)p, __ATOMIC_RELAXED, __HIP_MEMORY_SCOPE_AGENT);
}
__device__ __forceinline__ void st_agent_u64(void* p, u64 v) {
  __hip_atomic_store((u64*)p, v, __ATOMIC_RELAXED, __HIP_MEMORY_SCOPE_AGENT);
}
__device__ __forceinline__ void st_agent_u32(void* p, u32 v) {
  __hip_atomic_store((u32*)p, v, __ATOMIC_RELAXED, __HIP_MEMORY_SCOPE_AGENT);
}
__device__ __forceinline__ u32 ld_agent_u32(const void* p) {
  return __hip_atomic_load((const u32*)p, __ATOMIC_RELAXED, __HIP_MEMORY_SCOPE_AGENT);
}

// Persistent LSTM: 128 WGs x 512 thr.  Block b: pair-slot gA = b>>3 (0..15),
// u-slice j = b&7.  Phase p=0 runs group gA (rows [gA*32,+32)), phase p=1 runs
// group gA+16.  Both phases share the SAME u-slice -> same bf weight slab.
// Per phase the body is VERBATIM round-0 (stage -> MFMA -> gates -> store ->
// post).  Between a group's post and its next wait lies the other group's
// whole phase, hiding the IC exchange round-trip.  hs/gz are phase-serialized
// (barriers) and therefore shared; only c[] and ps duplicate per phase.
__global__ __launch_bounds__(512, 2)
void lstm_persist(const float* __restrict__ pricesT,
                  const float* __restrict__ Wx,
                  const float* __restrict__ bias,
                  const float* __restrict__ Wd,
                  const float* __restrict__ bd,
                  const float* __restrict__ Wp,
                  const float* __restrict__ bp,
                  const _Float16* __restrict__ WhT,
                  _Float16* __restrict__ hbuf,      // [2][1024][512]
                  u32* __restrict__ ctr,            // [32][8]
                  float* __restrict__ out)          // [1024][32]
{
  __shared__ __align__(16) _Float16 hs[ROWS_G][520];   // 33.3 KB (shared by phases)
  __shared__ __align__(16) float    gz[4][ROWS_G][66]; // 33.8 KB (shared by phases)
  __shared__ float ps[2][ROWS_G];

  const int tid = threadIdx.x;
  const int b   = blockIdx.x;       // 0..127
  const int gA  = b >> 3;           // pair-slot 0..15
  const int j   = b & 7;            // WG within group (same for both phases)
  const int u0  = j * U_WG;

  const int wv8 = tid >> 6;         // wave 0..7
  const int g   = wv8 & 3;          // gate 0..3
  const int cph = wv8 >> 2;         // col-half 0..1 (32 cols each)
  const int ln  = tid & 15;
  const int qd  = (tid >> 4) & 3;

  // ---- Wh slab -> B-fragments (128 VGPR): B[k = kk*32 + qd*8 + jj][n = ln] ----
  // Shared by both phases (same u-slice).
  half8 bf[16][2];
  #pragma unroll
  for (int kk = 0; kk < 16; ++kk) {
    #pragma unroll
    for (int ct = 0; ct < 2; ++ct) {
      int gcol = g*U_ + u0 + cph*32 + ct*16 + ln;   // global gate-col
      bf[kk][ct] = *(const half8*)&WhT[(size_t)gcol*U_ + kk*32 + qd*8];
    }
  }

  // gate-stage mapping: thread owns (row = tid&31, u4 = (tid>>5)*4 .. +4)
  const int grow = tid & 31;
  const int gu4  = (tid >> 5) * 4;          // 0..60 step 4
  float wxv[4][4], bv[4][4];
  #pragma unroll
  for (int gg = 0; gg < 4; ++gg)
    #pragma unroll
    for (int jj = 0; jj < 4; ++jj) {
      int ug = u0 + gu4 + jj;
      wxv[gg][jj] = Wx[gg*U_ + ug];
      bv[gg][jj]  = bias[gg*U_ + ug];
    }

  float c[2][4];
  #pragma unroll
  for (int p = 0; p < 2; ++p)
    #pragma unroll
    for (int e = 0; e < 4; ++e) c[p][e] = 0.f;

  for (int t = 0; t < T_; ++t) {
    #pragma unroll
    for (int p = 0; p < 2; ++p) {
      const int gid  = gA + p*16;
      const int row0 = gid * ROWS_G;
      u32* const myfl = ctr + gid*PER_G;
      const _Float16* hcur = hbuf + (size_t)(t & 1)*(B_*U_) + (size_t)row0*U_;
      _Float16* hnxt = hbuf + (size_t)((t + 1) & 1)*(B_*U_);

      // ---- wait: all 8 peers posted h(t) (flag >= t); wave 0 only ----
      if (wv8 == 0) {
        if (tid < ROWS_G) ps[p][tid] = pricesT[(size_t)t*B_ + row0 + tid];
        const int lane = tid & 63;
        bool ok;
        do {
          u32 v = (lane < PER_G) ? ld_agent_u32(&myfl[lane]) : 0xFFFFFFFFu;
          ok = (v >= (u32)t);
          if (!__all(ok)) { __builtin_amdgcn_s_sleep(1); ok = false; }
          else ok = true;
        } while (!ok);
      }
      __syncthreads();

      // ---- stage h tile: 32 rows x 512 halves = 4096 chunks of 8B ----
      #pragma unroll
      for (int it = 0; it < 8; ++it) {
        int id = tid + it*512;        // 0..4095
        int r  = id >> 7;             // row 0..31
        int ch = id & 127;            // 8B chunk
        u64 v = ld_agent_u64(&hcur[(size_t)r*U_ + ch*4]);
        *(u64*)&hs[r][ch*4] = v;
      }
      __syncthreads();

      // ---- z = h @ Wh: gate g, rows 32, cols [cph*32,+32), FULL K=512 ----
      f32x4 acc[2][2];
      #pragma unroll
      for (int rt = 0; rt < 2; ++rt)
        #pragma unroll
        for (int ct = 0; ct < 2; ++ct)
          #pragma unroll
          for (int r = 0; r < 4; ++r)
            acc[rt][ct][r] = 0.f;

      #pragma unroll
      for (int kk = 0; kk < 16; ++kk) {
        #pragma unroll
        for (int rt = 0; rt < 2; ++rt) {
          half8 afr = *(const half8*)&hs[rt*16 + ln][kk*32 + qd*8];  // A[m=ln][k=qd*8+jj]
          acc[rt][0] = __builtin_amdgcn_mfma_f32_16x16x32_f16(afr, bf[kk][0], acc[rt][0], 0, 0, 0);
          acc[rt][1] = __builtin_amdgcn_mfma_f32_16x16x32_f16(afr, bf[kk][1], acc[rt][1], 0, 0, 0);
        }
      }

      // ---- scatter z (C/D: row = qd*4+r, col = ln) ----
      #pragma unroll
      for (int rt = 0; rt < 2; ++rt)
        #pragma unroll
        for (int ct = 0; ct < 2; ++ct)
          #pragma unroll
          for (int r = 0; r < 4; ++r)
            gz[g][rt*16 + qd*4 + r][cph*32 + ct*16 + ln] = acc[rt][ct][r];
      __syncthreads();

      // ---- gate math (fp32); one packed 4xfp16 8B store per thread ----
      {
        float px = ps[p][grow];
        unsigned short hb[4];
        #pragma unroll
        for (int jj = 0; jj < 4; ++jj) {
          float zi = gz[0][grow][gu4+jj] + px*wxv[0][jj] + bv[0][jj];
          float zf = gz[1][grow][gu4+jj] + px*wxv[1][jj] + bv[1][jj];
          float zg = gz[2][grow][gu4+jj] + px*wxv[2][jj] + bv[2][jj];
          float zo = gz[3][grow][gu4+jj] + px*wxv[3][jj] + bv[3][jj];
          float ig = sigm(zi), fg = sigm(zf), gg = tanhf_fast(zg), og = sigm(zo);
          float cn = fg*c[p][jj] + ig*gg;
          c[p][jj] = cn;
          _Float16 hh = (_Float16)(og*tanhf_fast(cn));
          hb[jj] = __builtin_bit_cast(unsigned short, hh);
        }
        u64 pk = (u64)hb[0] | ((u64)hb[1] << 16) | ((u64)hb[2] << 32) | ((u64)hb[3] << 48);
        st_agent_u64(&hnxt[(size_t)(row0 + grow)*U_ + u0 + gu4], pk);
      }

      // ---- drain (syncthreads waits vmcnt(0) per wave), then post flag ----
      __syncthreads();
      if (tid == 0) st_agent_u32(&myfl[j], (u32)(t + 1));
    }
  }

  // ---- head: per phase-group, wait final h(256) then 4 rows each ----
  #pragma unroll
  for (int p = 0; p < 2; ++p) {
    const int gid  = gA + p*16;
    const int row0 = gid * ROWS_G;
    u32* const myfl = ctr + gid*PER_G;

    if (wv8 == 0) {
      const int lane = tid & 63;
      bool ok;
      do {
        u32 v = (lane < PER_G) ? ld_agent_u32(&myfl[lane]) : 0xFFFFFFFFu;
        ok = (v >= (u32)T_);
        if (!__all(ok)) { __builtin_amdgcn_s_sleep(1); ok = false; }
        else ok = true;
      } while (!ok);
    }
    __syncthreads();

    {
      const _Float16* hfin = hbuf;                                // parity of t=256 is 0
      float*    xrow = (float*)&gz[0][0][0];                      // [4][64]
      _Float16* hrow = (_Float16*)((char*)&gz[0][0][0] + 1024);   // [4][512]

      {
        int fl = tid*4;      // 512 thr x 8B = 4 rows x 512 halves
        int r2 = fl >> 9;
        int of = fl & 511;
        u64 v = ld_agent_u64(&hfin[(size_t)(row0 + j*4 + r2)*U_ + of]);
        *(u64*)&hrow[r2*U_ + of] = v;
      }
      __syncthreads();
      if (tid < 256) {
        int rr = tid >> 6;
        int kk = tid & 63;
        float a = bd[kk];
        for (int k2 = 0; k2 < U_; ++k2)
          a += (float)hrow[rr*U_ + k2] * Wd[(size_t)k2*64 + kk];
        a = fmaxf(a, 0.f);
        xrow[rr*64 + kk] = a;
      }
      __syncthreads();
      if (tid < 256 && (tid & 63) < 32) {
        int rr = tid >> 6;
        int kk = tid & 63;
        int brow = row0 + j*4 + rr;
        float o2 = bp[kk];
        #pragma unroll
        for (int j2 = 0; j2 < 64; ++j2)
          o2 += xrow[rr*64 + j2] * Wp[j2*32 + kk];
        out[(size_t)brow*32 + kk] = o2;
      }
    }
    __syncthreads();   // gz scratch reused by next phase
  }
}

extern "C" void kernel_launch(void* const* d_in, const int* in_sizes, int n_in,
                              void* d_out, int out_size, void* d_ws, size_t ws_size,
                              hipStream_t stream) {
  (void)in_sizes; (void)n_in; (void)out_size; (void)ws_size;
  const float* prices = (const float*)d_in[0];
  const float* Wx     = (const float*)d_in[1];
  const float* Wh     = (const float*)d_in[2];
  const float* bias   = (const float*)d_in[3];
  const float* Wd     = (const float*)d_in[4];
  const float* bd     = (const float*)d_in[5];
  const float* Wp     = (const float*)d_in[6];
  const float* bp     = (const float*)d_in[7];

  char* ws = (char*)d_ws;
  _Float16* WhT  = (_Float16*)(ws + WHT_OFF);
  _Float16* hbuf = (_Float16*)(ws + H_OFF);
  u32* ctr       = (u32*)(ws + CTR_OFF);
  float* pricesT = (float*)(ws + PT_OFF);

  // zero initial h (buffer 0) and the flags (ws is re-poisoned before every launch)
  hipMemsetAsync(hbuf, 0, (size_t)B_*U_*sizeof(_Float16), stream);
  hipMemsetAsync(ctr, 0, 32*PER_G*sizeof(u32), stream);

  prep_wht<<<dim3(4*U_), dim3(U_), 0, stream>>>(Wh, WhT);
  prep_pt<<<dim3(T_), dim3(256), 0, stream>>>(prices, pricesT);
  lstm_persist<<<dim3(128), dim3(512), 0, stream>>>(pricesT, Wx, bias, Wd, bd, Wp, bp,
                                                    WhT, hbuf, ctr, (float*)d_out);
}

// Round 6
// 1435.747 us; speedup vs baseline: 2.7821x; 2.0884x over previous
//
#include <hip/hip_runtime.h>

typedef _Float16 half8 __attribute__((ext_vector_type(8)));
typedef float    f32x4 __attribute__((ext_vector_type(4)));
typedef unsigned int u32;
typedef unsigned long long u64;

#define B_   1024
#define T_   256
#define U_   512

// 32 groups x 8 WGs; group owns 32 batch rows, WG owns u-slice of 64.
#define PER_G  8
#define ROWS_G 32
#define U_WG   64
#define HS_LD  516   // was 520: breaks 8-way bank aliasing on MFMA A-reads

// d_ws layout
static const size_t WHT_OFF = 0;                 // WhT fp16 [2048][512] = 2 MB
static const size_t H_OFF   = 2u*1024*1024;      // h ping-pong fp16 [2][1024][512] = 2 MB
static const size_t CTR_OFF = 4u*1024*1024;      // ctr u32 [32][8]
static const size_t PT_OFF  = 4u*1024*1024 + 65536;  // pricesT f32 [256][1024] = 1 MB

__global__ __launch_bounds__(512)
void prep_wht(const float* __restrict__ Wh, _Float16* __restrict__ WhT) {
  int j = blockIdx.x;   // 0..2047
  int k = threadIdx.x;  // 0..511
  WhT[(size_t)j*U_ + k] = (_Float16)Wh[(size_t)k*(4*U_) + j];
}

__global__ __launch_bounds__(256)
void prep_pt(const float* __restrict__ prices, float* __restrict__ pricesT) {
  int t = blockIdx.x;                 // 0..255
  for (int r = threadIdx.x; r < B_; r += 256)
    pricesT[(size_t)t*B_ + r] = prices[(size_t)r*T_ + t];
}

__device__ __forceinline__ float sigm(float x) { return 1.f/(1.f + __expf(-x)); }
__device__ __forceinline__ float tanhf_fast(float x) {
  float ax = fabsf(x);
  float e  = __expf(2.f*ax);          // large ax -> inf -> t = 1 (safe)
  float t  = 1.f - 2.f/(e + 1.f);
  return copysignf(t, x);
}

// Agent-scope (IC-coherent) ops — round-0-proven for all STORES and flag loads.
__device__ __forceinline__ u64 ld_agent_u64(const void* p) {
  return __hip_atomic_load((const u64*)p, __ATOMIC_RELAXED, __HIP_MEMORY_SCOPE_AGENT);
}
__device__ __forceinline__ void st_agent_u64(void* p, u64 v) {
  __hip_atomic_store((u64*)p, v, __ATOMIC_RELAXED, __HIP_MEMORY_SCOPE_AGENT);
}
__device__ __forceinline__ void st_agent_u32(void* p, u32 v) {
  __hip_atomic_store((u32*)p, v, __ATOMIC_RELAXED, __HIP_MEMORY_SCOPE_AGENT);
}
__device__ __forceinline__ u32 ld_agent_u32(const void* p) {
  return __hip_atomic_load((const u32*)p, __ATOMIC_RELAXED, __HIP_MEMORY_SCOPE_AGENT);
}

// Batched IC read for h staging: sc0 sc1 = read at the system coherence point
// (the same point the agent-scope stores commit to). NOT waited — caller
// issues many back-to-back (memory-level parallelism) then drains once.
// This replaces 8 serialized ~1100-cy atomic-load round-trips per thread.
__device__ __forceinline__ u64 ld_stage_u64(const void* p) {
  u64 v;
  asm volatile("global_load_dwordx2 %0, %1, off sc0 sc1" : "=v"(v) : "v"(p));
  return v;
}
__device__ __forceinline__ void vm_drain() {
  asm volatile("s_waitcnt vmcnt(0)" ::: "memory");
  __builtin_amdgcn_sched_barrier(0);
}

// Persistent LSTM: 256 WGs x 512 thr. WG (gid = b>>3, j = b&7):
// rows [gid*32,+32), u [j*64,+64).
// Wave w: gate g = w&3, col-half cph = w>>2 (cols [cph*32,+32)).
// Each wave: FULL K=512 chain (round-0-verbatim arithmetic),
// 2 row-tiles x 2 col-tiles, bf[16][2] = 128 VGPR resident.
// Exchange via agent(sc) ops at IC; flags ctr[gid][8], value = steps completed.
__global__ __launch_bounds__(512, 1)
void lstm_persist(const float* __restrict__ pricesT,
                  const float* __restrict__ Wx,
                  const float* __restrict__ bias,
                  const float* __restrict__ Wd,
                  const float* __restrict__ bd,
                  const float* __restrict__ Wp,
                  const float* __restrict__ bp,
                  const _Float16* __restrict__ WhT,
                  _Float16* __restrict__ hbuf,      // [2][1024][512]
                  u32* __restrict__ ctr,            // [32][8]
                  float* __restrict__ out)          // [1024][32]
{
  __shared__ __align__(16) _Float16 hs[ROWS_G][HS_LD]; // 32.3 KB
  __shared__ __align__(16) float    gz[4][ROWS_G][66]; // 33.8 KB
  __shared__ float ps[ROWS_G];

  const int tid = threadIdx.x;
  const int b   = blockIdx.x;
  const int gid = b >> 3;           // group 0..31
  const int j   = b & 7;            // WG within group
  const int row0 = gid * ROWS_G;
  const int u0   = j * U_WG;

  const int wv8 = tid >> 6;         // wave 0..7
  const int g   = wv8 & 3;          // gate 0..3
  const int cph = wv8 >> 2;         // col-half 0..1 (32 cols each)
  const int ln  = tid & 15;
  const int qd  = (tid >> 4) & 3;

  // ---- Wh slab -> B-fragments (128 VGPR): B[k = kk*32 + qd*8 + jj][n = ln] ----
  half8 bf[16][2];
  #pragma unroll
  for (int kk = 0; kk < 16; ++kk) {
    #pragma unroll
    for (int ct = 0; ct < 2; ++ct) {
      int gcol = g*U_ + u0 + cph*32 + ct*16 + ln;   // global gate-col
      bf[kk][ct] = *(const half8*)&WhT[(size_t)gcol*U_ + kk*32 + qd*8];
    }
  }

  // gate-stage mapping: thread owns (row = tid&31, u4 = (tid>>5)*4 .. +4)
  const int grow = tid & 31;
  const int gu4  = (tid >> 5) * 4;          // 0..60 step 4
  float wxv[4][4], bv[4][4];
  #pragma unroll
  for (int gg = 0; gg < 4; ++gg)
    #pragma unroll
    for (int jj = 0; jj < 4; ++jj) {
      int ug = u0 + gu4 + jj;
      wxv[gg][jj] = Wx[gg*U_ + ug];
      bv[gg][jj]  = bias[gg*U_ + ug];
    }

  float c[4];
  #pragma unroll
  for (int e = 0; e < 4; ++e) c[e] = 0.f;

  u32* const myfl = ctr + gid*PER_G;

  for (int t = 0; t < T_; ++t) {
    const _Float16* hcur = hbuf + (size_t)(t & 1)*(B_*U_) + (size_t)row0*U_;
    _Float16* hnxt = hbuf + (size_t)((t + 1) & 1)*(B_*U_);

    // ---- wait: all 8 peers posted h(t) (flag >= t); wave 0 only ----
    if (wv8 == 0) {
      if (tid < ROWS_G) ps[tid] = pricesT[(size_t)t*B_ + row0 + tid];  // overlap w/ poll
      const int lane = tid & 63;
      bool ok;
      do {
        u32 v = (lane < PER_G) ? ld_agent_u32(&myfl[lane]) : 0xFFFFFFFFu;
        ok = (v >= (u32)t);
        if (!__all(ok)) { __builtin_amdgcn_s_sleep(1); ok = false; }
        else ok = true;
      } while (!ok);
    }
    __syncthreads();

    // ---- stage h tile: 32 rows x 512 halves = 4096 chunks of 8B ----
    // Batched: issue all 8 IC loads, ONE drain, then 8 LDS writes.
    {
      u64 vbuf[8];
      #pragma unroll
      for (int it = 0; it < 8; ++it) {
        int id = tid + it*512;        // 0..4095
        int r  = id >> 7;             // row 0..31
        int ch = id & 127;            // 8B chunk
        vbuf[it] = ld_stage_u64(&hcur[(size_t)r*U_ + ch*4]);
      }
      vm_drain();
      #pragma unroll
      for (int it = 0; it < 8; ++it) {
        int id = tid + it*512;
        int r  = id >> 7;
        int ch = id & 127;
        *(u64*)&hs[r][ch*4] = vbuf[it];
      }
    }
    __syncthreads();

    // ---- z = h @ Wh: gate g, rows 32, cols [cph*32,+32), FULL K=512 chain ----
    f32x4 acc[2][2];
    #pragma unroll
    for (int rt = 0; rt < 2; ++rt)
      #pragma unroll
      for (int ct = 0; ct < 2; ++ct)
        #pragma unroll
        for (int r = 0; r < 4; ++r)
          acc[rt][ct][r] = 0.f;

    #pragma unroll
    for (int kk = 0; kk < 16; ++kk) {
      #pragma unroll
      for (int rt = 0; rt < 2; ++rt) {
        half8 afr = *(const half8*)&hs[rt*16 + ln][kk*32 + qd*8];  // A[m=ln][k=qd*8+jj]
        acc[rt][0] = __builtin_amdgcn_mfma_f32_16x16x32_f16(afr, bf[kk][0], acc[rt][0], 0, 0, 0);
        acc[rt][1] = __builtin_amdgcn_mfma_f32_16x16x32_f16(afr, bf[kk][1], acc[rt][1], 0, 0, 0);
      }
    }

    // ---- scatter z (C/D: row = qd*4+r, col = ln) ----
    #pragma unroll
    for (int rt = 0; rt < 2; ++rt)
      #pragma unroll
      for (int ct = 0; ct < 2; ++ct)
        #pragma unroll
        for (int r = 0; r < 4; ++r)
          gz[g][rt*16 + qd*4 + r][cph*32 + ct*16 + ln] = acc[rt][ct][r];
    __syncthreads();

    // ---- gate math (fp32); one packed 4xfp16 8B store per thread ----
    {
      float px = ps[grow];
      unsigned short hb[4];
      #pragma unroll
      for (int jj = 0; jj < 4; ++jj) {
        float zi = gz[0][grow][gu4+jj] + px*wxv[0][jj] + bv[0][jj];
        float zf = gz[1][grow][gu4+jj] + px*wxv[1][jj] + bv[1][jj];
        float zg = gz[2][grow][gu4+jj] + px*wxv[2][jj] + bv[2][jj];
        float zo = gz[3][grow][gu4+jj] + px*wxv[3][jj] + bv[3][jj];
        float ig = sigm(zi), fg = sigm(zf), gg = tanhf_fast(zg), og = sigm(zo);
        float cn = fg*c[jj] + ig*gg;
        c[jj] = cn;
        _Float16 hh = (_Float16)(og*tanhf_fast(cn));
        hb[jj] = __builtin_bit_cast(unsigned short, hh);
      }
      u64 pk = (u64)hb[0] | ((u64)hb[1] << 16) | ((u64)hb[2] << 32) | ((u64)hb[3] << 48);
      st_agent_u64(&hnxt[(size_t)(row0 + grow)*U_ + u0 + gu4], pk);
    }

    // ---- drain (syncthreads waits vmcnt(0) per wave), then post flag = t+1 ----
    __syncthreads();
    if (tid == 0) st_agent_u32(&myfl[j], (u32)(t + 1));
  }

  // ---- wait group's final h(256) ----
  if (wv8 == 0) {
    const int lane = tid & 63;
    bool ok;
    do {
      u32 v = (lane < PER_G) ? ld_agent_u32(&myfl[lane]) : 0xFFFFFFFFu;
      ok = (v >= (u32)T_);
      if (!__all(ok)) { __builtin_amdgcn_s_sleep(1); ok = false; }
      else ok = true;
    } while (!ok);
  }
  __syncthreads();

  // ---- fused head: 4 rows: row0 + j*4 .. +4 ----
  {
    const _Float16* hfin = hbuf;                                // parity of t=256 is 0
    float*    xrow = (float*)&gz[0][0][0];                      // [4][64]
    _Float16* hrow = (_Float16*)((char*)&gz[0][0][0] + 1024);   // [4][512]

    {
      int fl = tid*4;      // 512 thr x 8B = 4 rows x 512 halves
      int r2 = fl >> 9;
      int of = fl & 511;
      u64 v = ld_agent_u64(&hfin[(size_t)(row0 + j*4 + r2)*U_ + of]);
      *(u64*)&hrow[r2*U_ + of] = v;
    }
    __syncthreads();
    if (tid < 256) {
      int rr = tid >> 6;
      int kk = tid & 63;
      float a = bd[kk];
      for (int k2 = 0; k2 < U_; ++k2)
        a += (float)hrow[rr*U_ + k2] * Wd[(size_t)k2*64 + kk];
      a = fmaxf(a, 0.f);
      xrow[rr*64 + kk] = a;
    }
    __syncthreads();
    if (tid < 256 && (tid & 63) < 32) {
      int rr = tid >> 6;
      int kk = tid & 63;
      int brow = row0 + j*4 + rr;
      float o2 = bp[kk];
      #pragma unroll
      for (int j2 = 0; j2 < 64; ++j2)
        o2 += xrow[rr*64 + j2] * Wp[j2*32 + kk];
      out[(size_t)brow*32 + kk] = o2;
    }
  }
}

extern "C" void kernel_launch(void* const* d_in, const int* in_sizes, int n_in,
                              void* d_out, int out_size, void* d_ws, size_t ws_size,
                              hipStream_t stream) {
  (void)in_sizes; (void)n_in; (void)out_size; (void)ws_size;
  const float* prices = (const float*)d_in[0];
  const float* Wx     = (const float*)d_in[1];
  const float* Wh     = (const float*)d_in[2];
  const float* bias   = (const float*)d_in[3];
  const float* Wd     = (const float*)d_in[4];
  const float* bd     = (const float*)d_in[5];
  const float* Wp     = (const float*)d_in[6];
  const float* bp     = (const float*)d_in[7];

  char* ws = (char*)d_ws;
  _Float16* WhT  = (_Float16*)(ws + WHT_OFF);
  _Float16* hbuf = (_Float16*)(ws + H_OFF);
  u32* ctr       = (u32*)(ws + CTR_OFF);
  float* pricesT = (float*)(ws + PT_OFF);

  // zero initial h (buffer 0) and the flags (ws is re-poisoned before every launch)
  hipMemsetAsync(hbuf, 0, (size_t)B_*U_*sizeof(_Float16), stream);
  hipMemsetAsync(ctr, 0, 32*PER_G*sizeof(u32), stream);

  prep_wht<<<dim3(4*U_), dim3(U_), 0, stream>>>(Wh, WhT);
  prep_pt<<<dim3(T_), dim3(256), 0, stream>>>(prices, pricesT);
  lstm_persist<<<dim3(256), dim3(512), 0, stream>>>(pricesT, Wx, bias, Wd, bd, Wp, bp,
                                                    WhT, hbuf, ctr, (float*)d_out);
}